// Round 10
// baseline (65.961 us; speedup 1.0000x reference)
//
#include <hip/hip_runtime.h>
#include <hip/hip_bf16.h>

#define DD 512
#define NN 8
#define LL0 128
#define LL1 256

// 2 * log2(e): pre-scale so tanh(t) needs only v_exp_f32 (2^x).
#define LOG2E2 2.8853900817779268f

typedef float f32x4 __attribute__((ext_vector_type(4)));
typedef __bf16 bf16x8 __attribute__((ext_vector_type(8)));

__device__ __forceinline__ float fexp2(float x) {
#if __has_builtin(__builtin_amdgcn_exp2f)
    return __builtin_amdgcn_exp2f(x);
#else
    float r; asm("v_exp_f32 %0, %1" : "=v"(r) : "v"(x)); return r;
#endif
}
__device__ __forceinline__ float frcp(float x) {
#if __has_builtin(__builtin_amdgcn_rcpf)
    return __builtin_amdgcn_rcpf(x);
#else
    float r; asm("v_rcp_f32 %0, %1" : "=v"(r) : "v"(x)); return r;
#endif
}

// sigma2(t2) = 1/(2^t2 + 1); tanh(t) = 1 - 2*sigma2(2*log2e*t).
__device__ __forceinline__ float sig2(float t2) {
    return frcp(fexp2(t2) + 1.0f);
}

// fp32 -> bf16 round-to-nearest-even (normals; inputs are well-scaled).
__device__ __forceinline__ unsigned short f2bf(float f) {
    unsigned int u = __float_as_uint(f);
    u += 0x7fffu + ((u >> 16) & 1u);
    return (unsigned short)(u >> 16);
}

// ---------------------------------------------------------------------------
// Kernel 0a: mask compaction (one block per n).  [round-5 verified]
// bidx[n][j] = j-th valid b (padded 0), jinv[n][b] = j or -1, cnt[n].
// ---------------------------------------------------------------------------
__global__ __launch_bounds__(256) void compact_kernel(
    const int* __restrict__ mask, int* __restrict__ bidx,
    int* __restrict__ jinv, int* __restrict__ cnt)
{
    __shared__ int wsum[4];
    int n = blockIdx.x, b = threadIdx.x;
    int v = (mask[n * LL1 + b] != 0) ? 1 : 0;
    unsigned long long bal = __ballot(v);
    int lane = b & 63, wv = b >> 6;
    int wpre = __popcll(bal & ((1ull << lane) - 1ull));
    if (lane == 63) wsum[wv] = wpre + v;     // wave total
    bidx[n * LL1 + b] = 0;                   // padding default
    __syncthreads();
    int base = 0;
    #pragma unroll
    for (int i = 0; i < 4; ++i) base += (i < wv) ? wsum[i] : 0;
    int pos = base + wpre;
    if (v) {
        bidx[n * LL1 + pos] = b;
        jinv[n * LL1 + b] = pos;
    } else {
        jinv[n * LL1 + b] = -1;
    }
    if (b == 255) cnt[n] = pos + v;          // total valid count
}

// ---------------------------------------------------------------------------
// Kernel 0b: convert x|m -> A16[3072][512] bf16, W -> W16[512][1024] bf16.
// ---------------------------------------------------------------------------
__global__ __launch_bounds__(256) void cvt_kernel(
    const float* __restrict__ x, const float* __restrict__ m,
    const float* __restrict__ W,
    unsigned short* __restrict__ A16, unsigned short* __restrict__ W16)
{
    size_t i4 = ((size_t)blockIdx.x * 256 + threadIdx.x) * 4;
    const float* src;
    unsigned short* dst;
    if (i4 < (size_t)3072 * 512) {                 // A-part (x then m)
        src = (i4 < (size_t)1024 * 512) ? x + i4 : m + (i4 - (size_t)1024 * 512);
        dst = A16 + i4;
    } else {                                       // W-part
        size_t j = i4 - (size_t)3072 * 512;
        src = W + j; dst = W16 + j;
    }
    float4 v = *(const float4*)src;
    ushort4 o = make_ushort4(f2bf(v.x), f2bf(v.y), f2bf(v.z), f2bf(v.w));
    *(ushort4*)dst = o;
}

// ---------------------------------------------------------------------------
// Kernel 1: MFMA bf16 projection GEMM, fused bias + LOG2E2 epilogue.
//   xm[row][e] = LOG2E2 * (sum_k A16[row][k]*W16[e][koff+k] + (row<1024 ? Wb[e] : 0))
// [round-9 verified]
// ---------------------------------------------------------------------------
__global__ __launch_bounds__(256) void mfma_proj_kernel(
    const unsigned short* __restrict__ A16, const unsigned short* __restrict__ W16,
    const float* __restrict__ Wb, float* __restrict__ xm)
{
    __shared__ unsigned short As[128][72];
    __shared__ unsigned short Bs[64][72];

    int e0   = blockIdx.x * 64;
    int row0 = blockIdx.y * 128;
    bool isx = row0 < (NN * LL0);
    int koff = isx ? 0 : DD;

    int tid  = threadIdx.x;
    int wid  = tid >> 6;
    int lane = tid & 63;
    int l15  = lane & 15, lk = lane >> 4;

    int sar = tid >> 1, sak = (tid & 1) * 32;
    int sbr = tid >> 2, sbk = (tid & 3) * 16;

    const unsigned short* Ap = A16 + (size_t)(row0 + sar) * DD + sak;
    const unsigned short* Bp = W16 + (size_t)(e0 + sbr) * (2 * DD) + koff + sbk;

    uint4 a0 = *(const uint4*)(Ap);
    uint4 a1 = *(const uint4*)(Ap + 8);
    uint4 a2 = *(const uint4*)(Ap + 16);
    uint4 a3 = *(const uint4*)(Ap + 24);
    uint4 b0 = *(const uint4*)(Bp);
    uint4 b1 = *(const uint4*)(Bp + 8);

    f32x4 acc[2][4] = {};

    for (int kt = 0; kt < 8; ++kt) {
        if (kt) __syncthreads();
        *(uint4*)&As[sar][sak + 0]  = a0;
        *(uint4*)&As[sar][sak + 8]  = a1;
        *(uint4*)&As[sar][sak + 16] = a2;
        *(uint4*)&As[sar][sak + 24] = a3;
        *(uint4*)&Bs[sbr][sbk + 0]  = b0;
        *(uint4*)&Bs[sbr][sbk + 8]  = b1;
        if (kt < 7) {
            int ko = (kt + 1) * 64;
            a0 = *(const uint4*)(Ap + ko);
            a1 = *(const uint4*)(Ap + ko + 8);
            a2 = *(const uint4*)(Ap + ko + 16);
            a3 = *(const uint4*)(Ap + ko + 24);
            b0 = *(const uint4*)(Bp + ko);
            b1 = *(const uint4*)(Bp + ko + 8);
        }
        __syncthreads();

        #pragma unroll
        for (int kb = 0; kb < 2; ++kb) {
            bf16x8 af0 = *(const bf16x8*)&As[wid * 32 + l15][kb * 32 + lk * 8];
            bf16x8 af1 = *(const bf16x8*)&As[wid * 32 + 16 + l15][kb * 32 + lk * 8];
            #pragma unroll
            for (int ni = 0; ni < 4; ++ni) {
                bf16x8 bf = *(const bf16x8*)&Bs[ni * 16 + l15][kb * 32 + lk * 8];
                acc[0][ni] = __builtin_amdgcn_mfma_f32_16x16x32_bf16(af0, bf, acc[0][ni], 0, 0, 0);
                acc[1][ni] = __builtin_amdgcn_mfma_f32_16x16x32_bf16(af1, bf, acc[1][ni], 0, 0, 0);
            }
        }
    }

    #pragma unroll
    for (int ni = 0; ni < 4; ++ni) {
        int col = e0 + ni * 16 + l15;
        float bv = isx ? Wb[col] : 0.0f;
        #pragma unroll
        for (int mi = 0; mi < 2; ++mi) {
            #pragma unroll
            for (int r = 0; r < 4; ++r) {
                int row = row0 + wid * 32 + mi * 16 + lk * 4 + r;
                xm[(size_t)row * DD + col] = LOG2E2 * (acc[mi][ni][r] + bv);
            }
        }
    }
}

// ---------------------------------------------------------------------------
// Kernel 2: logits on COMPACTED b only, staging from fused xm plane.
//   wpart[dc][n][a][j] = sum_{d in chunk dc} V[d] * sig2(xm[a-row] + xm[bidx[j]-row])
// Tile 32a x 32j x 64d, 2a x 2j micro-tile. Early-exit when jbase >= cnt[n].
// Grid (8, 32, 8) = 2048 static, ~55% active (~4.4/CU). LDS 17.4 KB.
// ---------------------------------------------------------------------------
__global__ __launch_bounds__(256, 4) void logits_kernel(
    const float* __restrict__ xm, const float* __restrict__ Vw,
    const int* __restrict__ bidx, const int* __restrict__ cnt,
    float* __restrict__ wpart)
{
    __shared__ __attribute__((aligned(16))) float xs[64][34];  // [d][a: 32+2]
    __shared__ __attribute__((aligned(16))) float ms[64][34];  // [d][j: 32+2]
    __shared__ __attribute__((aligned(16))) float vsh[64];

    int n  = blockIdx.z;
    int bt = blockIdx.x;          // compact j-tile of 32
    int at = blockIdx.y & 3;      // 0..3 : 32 a-rows
    int dc = blockIdx.y >> 2;     // 0..7 : 64-d chunk
    int jbase = bt * 32;
    if (jbase >= cnt[n]) return;

    int tid = threadIdx.x;
    int ty = tid >> 4, tx = tid & 15;

    // ---- stage x-part: 32 rows x 64 d
    {
        int r  = tid & 31;
        int c8 = (tid >> 5) * 8;
        const float* src = xm + ((size_t)(n * LL0 + at * 32) + r) * DD + dc * 64 + c8;
        float4 v0 = *(const float4*)(src);
        float4 v1 = *(const float4*)(src + 4);
        xs[c8 + 0][r] = v0.x; xs[c8 + 1][r] = v0.y;
        xs[c8 + 2][r] = v0.z; xs[c8 + 3][r] = v0.w;
        xs[c8 + 4][r] = v1.x; xs[c8 + 5][r] = v1.y;
        xs[c8 + 6][r] = v1.z; xs[c8 + 7][r] = v1.w;
    }
    // ---- stage m-part: 32 GATHERED rows x 64 d (m-rows at xm row 1024+)
    {
        int r  = tid & 31;
        int c8 = (tid >> 5) * 8;
        int bj = bidx[n * LL1 + jbase + r];          // pad -> row 0 (unused)
        const float* src = xm + ((size_t)(NN * LL0 + n * LL1 + bj)) * DD + dc * 64 + c8;
        float4 v0 = *(const float4*)(src);
        float4 v1 = *(const float4*)(src + 4);
        ms[c8 + 0][r] = v0.x; ms[c8 + 1][r] = v0.y;
        ms[c8 + 2][r] = v0.z; ms[c8 + 3][r] = v0.w;
        ms[c8 + 4][r] = v1.x; ms[c8 + 5][r] = v1.y;
        ms[c8 + 6][r] = v1.z; ms[c8 + 7][r] = v1.w;
        if (tid < 16)
            *(float4*)&vsh[tid * 4] = *(const float4*)(Vw + dc * 64 + tid * 4);
    }
    __syncthreads();

    float acc[2][2] = {};

    #pragma unroll 8
    for (int kk = 0; kk < 64; ++kk) {
        float2 xa = *(const float2*)&xs[kk][ty * 2];
        float2 mb = *(const float2*)&ms[kk][tx * 2];
        float  vv = vsh[kk];
        acc[0][0] = fmaf(vv, sig2(xa.x + mb.x), acc[0][0]);
        acc[0][1] = fmaf(vv, sig2(xa.x + mb.y), acc[0][1]);
        acc[1][0] = fmaf(vv, sig2(xa.y + mb.x), acc[1][0]);
        acc[1][1] = fmaf(vv, sig2(xa.y + mb.y), acc[1][1]);
    }

    const size_t P = (size_t)NN * LL0 * LL1;
    float* wp = wpart + (size_t)dc * P
              + ((size_t)n * LL0 + at * 32 + ty * 2) * LL1 + jbase + tx * 2;
    *(float2*)(wp)       = make_float2(acc[0][0], acc[0][1]);
    *(float2*)(wp + LL1) = make_float2(acc[1][0], acc[1][1]);
}

// ---------------------------------------------------------------------------
// Kernel 3: masked softmax. Gathers 8 compact planes via jinv, -2 scale,
// softmax over valid b (masked -> exactly 0), dense write into plane 0.
// ---------------------------------------------------------------------------
__global__ __launch_bounds__(256) void softmax_kernel(
    float* __restrict__ wpart, const int* __restrict__ jinv)
{
    __shared__ float red[4];
    __shared__ float red2[4];
    const size_t P = (size_t)NN * LL0 * LL1;
    int row = blockIdx.x;          // n*L0 + a
    int n = row >> 7;
    int b = threadIdx.x;
    size_t rowoff = (size_t)row * LL1;

    int j = jinv[n * LL1 + b];
    float w = -1e30f;
    if (j >= 0) {
        float s8 = 0.f;
        #pragma unroll
        for (int p = 0; p < 8; ++p) s8 += wpart[(size_t)p * P + rowoff + j];
        w = -2.0f * s8;
    }

    float mx = w;
    #pragma unroll
    for (int off = 32; off; off >>= 1) mx = fmaxf(mx, __shfl_xor(mx, off));
    int wv = threadIdx.x >> 6;
    if ((threadIdx.x & 63) == 0) red[wv] = mx;
    __syncthreads();
    mx = fmaxf(fmaxf(red[0], red[1]), fmaxf(red[2], red[3]));

    float e = (j >= 0) ? __expf(w - mx) : 0.f;
    float s = e;
    #pragma unroll
    for (int off = 32; off; off >>= 1) s += __shfl_xor(s, off);
    if ((threadIdx.x & 63) == 0) red2[wv] = s;
    __syncthreads();
    s = red2[0] + red2[1] + red2[2] + red2[3];

    wpart[rowoff + b] = e / s;     // dense write into plane 0 (reads done first)
}

// ---------------------------------------------------------------------------
// Kernel 4: v[n,a,d] = sum_b w[n,a,b] * m[n,b,d].  [round-8/9 verified]
// ---------------------------------------------------------------------------
__global__ __launch_bounds__(256, 4) void vgemm_kernel(
    const float* __restrict__ wbuf, const float* __restrict__ m,
    float* __restrict__ out)
{
    __shared__ float wt[32][36];   // [k][a: 32+4]
    __shared__ float mt[32][68];   // [k][d: 64+4]

    int n  = blockIdx.z;
    int a0 = blockIdx.y * 32;
    int d0 = blockIdx.x * 64;
    int tid = threadIdx.x;
    int ty = tid >> 4, tx = tid & 15;

    const float* wrow = wbuf + ((size_t)n * LL0 + a0) * LL1;
    const float* mrow = m + (size_t)n * LL1 * DD;

    float acc[2][4] = {};
    for (int k0 = 0; k0 < LL1; k0 += 32) {
        {
            int r  = tid >> 3;            // a-row 0..31
            int c4 = (tid & 7) * 4;       // k 0..28
            float4 wv = *(const float4*)(wrow + (size_t)r * LL1 + k0 + c4);
            wt[c4 + 0][r] = wv.x; wt[c4 + 1][r] = wv.y;
            wt[c4 + 2][r] = wv.z; wt[c4 + 3][r] = wv.w;
        }
        {
            int r  = tid >> 3;            // k-row 0..31
            int c8 = (tid & 7) * 8;       // d 0..56
            const float* src = mrow + (size_t)(k0 + r) * DD + d0 + c8;
            *(float4*)&mt[r][c8]     = *(const float4*)(src);
            *(float4*)&mt[r][c8 + 4] = *(const float4*)(src + 4);
        }
        __syncthreads();
        #pragma unroll 8
        for (int kk = 0; kk < 32; ++kk) {
            float2 av = *(const float2*)&wt[kk][ty * 2];
            float4 bv = *(const float4*)&mt[kk][tx * 4];
            acc[0][0] = fmaf(av.x, bv.x, acc[0][0]);
            acc[0][1] = fmaf(av.x, bv.y, acc[0][1]);
            acc[0][2] = fmaf(av.x, bv.z, acc[0][2]);
            acc[0][3] = fmaf(av.x, bv.w, acc[0][3]);
            acc[1][0] = fmaf(av.y, bv.x, acc[1][0]);
            acc[1][1] = fmaf(av.y, bv.y, acc[1][1]);
            acc[1][2] = fmaf(av.y, bv.z, acc[1][2]);
            acc[1][3] = fmaf(av.y, bv.w, acc[1][3]);
        }
        __syncthreads();
    }
    float* op = out + ((size_t)n * LL0 + a0 + ty * 2) * DD + d0 + tx * 4;
    *(float4*)(op)      = make_float4(acc[0][0], acc[0][1], acc[0][2], acc[0][3]);
    *(float4*)(op + DD) = make_float4(acc[1][0], acc[1][1], acc[1][2], acc[1][3]);
}

extern "C" void kernel_launch(void* const* d_in, const int* in_sizes, int n_in,
                              void* d_out, int out_size, void* d_ws, size_t ws_size,
                              hipStream_t stream) {
    const float* x    = (const float*)d_in[0];
    const float* m    = (const float*)d_in[1];
    const int*   mask = (const int*)d_in[2];
    const float* W_w  = (const float*)d_in[3];
    const float* W_b  = (const float*)d_in[4];
    const float* V_w  = (const float*)d_in[5];
    const float* V_b  = (const float*)d_in[6];
    (void)V_b; // additive constant — cancels under softmax shift-invariance
    float* out = (float*)d_out;

    // Workspace (floats):
    //   xm    : 3072*512              = 1,572,864  (fused scaled/biased projections)
    //   wpart : 8 * 8*128*256         = 2,097,152  (compact logit partials; plane 0 -> w)
    //   A16   : 3072*512 bf16         =   786,432  float-equiv
    //   W16   : 512*1024 bf16         =   262,144  float-equiv
    //   ints  : bidx 2048 + jinv 2048 + cnt 8
    // Total: ~18.9 MB + 16 KB
    float* xm    = (float*)d_ws;
    float* wpart = xm + (size_t)3072 * 512;
    unsigned short* A16 = (unsigned short*)(wpart + (size_t)8 * NN * LL0 * LL1);
    unsigned short* W16 = A16 + (size_t)3072 * 512;
    int* bidx = (int*)(W16 + (size_t)512 * 1024);
    int* jinv = bidx + NN * LL1;
    int* cnt  = jinv + NN * LL1;

    compact_kernel<<<dim3(8), 256, 0, stream>>>(mask, bidx, jinv, cnt);
    cvt_kernel<<<dim3(2048), 256, 0, stream>>>(x, m, W_w, A16, W16);
    mfma_proj_kernel<<<dim3(8, 24), 256, 0, stream>>>(A16, W16, W_b, xm);
    logits_kernel<<<dim3(8, 32, 8), 256, 0, stream>>>(xm, V_w, bidx, cnt, wpart);
    softmax_kernel<<<dim3(1024), 256, 0, stream>>>(wpart, jinv);
    vgemm_kernel<<<dim3(8, 4, 8), 256, 0, stream>>>(wpart, m, out);
}

// Round 11
// 64.075 us; speedup vs baseline: 1.0294x; 1.0294x over previous
//
#include <hip/hip_runtime.h>
#include <hip/hip_bf16.h>

#define DD 512
#define NN 8
#define LL0 128
#define LL1 256

// 2 * log2(e): pre-scale so tanh(t) needs only v_exp_f32 (2^x).
#define LOG2E2 2.8853900817779268f

// split-K partial plane stride (floats): 3072 rows x 512 e
#define PSTR ((size_t)3072 * 512)

typedef float f32x4 __attribute__((ext_vector_type(4)));
typedef __bf16 bf16x8 __attribute__((ext_vector_type(8)));

__device__ __forceinline__ float fexp2(float x) {
#if __has_builtin(__builtin_amdgcn_exp2f)
    return __builtin_amdgcn_exp2f(x);
#else
    float r; asm("v_exp_f32 %0, %1" : "=v"(r) : "v"(x)); return r;
#endif
}
__device__ __forceinline__ float frcp(float x) {
#if __has_builtin(__builtin_amdgcn_rcpf)
    return __builtin_amdgcn_rcpf(x);
#else
    float r; asm("v_rcp_f32 %0, %1" : "=v"(r) : "v"(x)); return r;
#endif
}

// sigma2(t2) = 1/(2^t2 + 1); tanh(t) = 1 - 2*sigma2(2*log2e*t).
__device__ __forceinline__ float sig2(float t2) {
    return frcp(fexp2(t2) + 1.0f);
}

// fp32 -> bf16 round-to-nearest-even (normals; inputs are well-scaled).
__device__ __forceinline__ unsigned short f2bf(float f) {
    unsigned int u = __float_as_uint(f);
    u += 0x7fffu + ((u >> 16) & 1u);
    return (unsigned short)(u >> 16);
}

// ---------------------------------------------------------------------------
// Kernel 0: convert x|m -> A16[3072][512] bf16, W -> W16[512][1024] bf16.
// ---------------------------------------------------------------------------
__global__ __launch_bounds__(256) void cvt_kernel(
    const float* __restrict__ x, const float* __restrict__ m,
    const float* __restrict__ W,
    unsigned short* __restrict__ A16, unsigned short* __restrict__ W16)
{
    size_t i4 = ((size_t)blockIdx.x * 256 + threadIdx.x) * 4;
    const float* src;
    unsigned short* dst;
    if (i4 < (size_t)3072 * 512) {                 // A-part (x then m)
        src = (i4 < (size_t)1024 * 512) ? x + i4 : m + (i4 - (size_t)1024 * 512);
        dst = A16 + i4;
    } else {                                       // W-part
        size_t j = i4 - (size_t)3072 * 512;
        src = W + j; dst = W16 + j;
    }
    float4 v = *(const float4*)src;
    ushort4 o = make_ushort4(f2bf(v.x), f2bf(v.y), f2bf(v.z), f2bf(v.w));
    *(ushort4*)dst = o;
}

// ---------------------------------------------------------------------------
// Kernel 1: MFMA bf16 projection GEMM v3, split-K=2.
//   pp[kz][row][e] = sum_{k in half kz} A16[row][k] * W16[e][koff+k]
// Tile 64(rows) x 64(e), K-step 64, 4 waves (wave w owns rows w*16..+15).
// LDS rows padded to 68 bf16 (136 B): fragment reads are 2x ds_read_b64,
// bank = (2*l15 + 4*lk) mod 32 -> CONFLICT-FREE (r9's 144B-row b128 reads
// were 8-way conflicted -> ~19 us).
// Grid (8, 48, 2) = 768 blocks = 3.0/CU exact. Bias/scale -> logits staging.
// ---------------------------------------------------------------------------
__global__ __launch_bounds__(256, 3) void mfma_proj_kernel(
    const unsigned short* __restrict__ A16, const unsigned short* __restrict__ W16,
    float* __restrict__ pp)
{
    __shared__ unsigned short As[64][68];
    __shared__ unsigned short Bs[64][68];

    int e0   = blockIdx.x * 64;
    int row0 = blockIdx.y * 64;
    int kb0  = blockIdx.z * 256;       // K-half base
    bool isx = row0 < (NN * LL0);
    int koff = isx ? 0 : DD;

    int tid  = threadIdx.x;
    int wid  = tid >> 6;               // wave 0..3 -> rows wid*16..+15
    int lane = tid & 63;
    int l15  = lane & 15, lk = lane >> 4;   // lk 0..3

    int srow = tid >> 2;               // staging row 0..63
    int scol = (tid & 3) * 16;         // staging k-col 0,16,32,48 (bf16 units)

    const unsigned short* Ap = A16 + (size_t)(row0 + srow) * DD + kb0 + scol;
    const unsigned short* Bp = W16 + (size_t)(e0 + srow) * (2 * DD) + koff + kb0 + scol;

    uint4 a0 = *(const uint4*)(Ap);        // 8 bf16
    uint4 a1 = *(const uint4*)(Ap + 8);
    uint4 b0 = *(const uint4*)(Bp);
    uint4 b1 = *(const uint4*)(Bp + 8);

    f32x4 acc[4] = {};

    for (int kt = 0; kt < 4; ++kt) {
        if (kt) __syncthreads();       // prior step's LDS reads complete
        // 16 bf16 per tile -> 4x 8B writes (2-way worst case on banks)
        *(uint2*)&As[srow][scol + 0]  = make_uint2(a0.x, a0.y);
        *(uint2*)&As[srow][scol + 4]  = make_uint2(a0.z, a0.w);
        *(uint2*)&As[srow][scol + 8]  = make_uint2(a1.x, a1.y);
        *(uint2*)&As[srow][scol + 12] = make_uint2(a1.z, a1.w);
        *(uint2*)&Bs[srow][scol + 0]  = make_uint2(b0.x, b0.y);
        *(uint2*)&Bs[srow][scol + 4]  = make_uint2(b0.z, b0.w);
        *(uint2*)&Bs[srow][scol + 8]  = make_uint2(b1.x, b1.y);
        *(uint2*)&Bs[srow][scol + 12] = make_uint2(b1.z, b1.w);
        if (kt < 3) {                  // prefetch next K-step
            int ko = (kt + 1) * 64;
            a0 = *(const uint4*)(Ap + ko);
            a1 = *(const uint4*)(Ap + ko + 8);
            b0 = *(const uint4*)(Bp + ko);
            b1 = *(const uint4*)(Bp + ko + 8);
        }
        __syncthreads();               // staged data visible

        #pragma unroll
        for (int kb = 0; kb < 2; ++kb) {
            union { unsigned int u[4]; bf16x8 v; } af;
            {
                const uint2* p = (const uint2*)&As[wid * 16 + l15][kb * 32 + lk * 8];
                uint2 lo = p[0], hi = p[1];
                af.u[0] = lo.x; af.u[1] = lo.y; af.u[2] = hi.x; af.u[3] = hi.y;
            }
            #pragma unroll
            for (int ni = 0; ni < 4; ++ni) {
                union { unsigned int u[4]; bf16x8 v; } bf;
                const uint2* p = (const uint2*)&Bs[ni * 16 + l15][kb * 32 + lk * 8];
                uint2 lo = p[0], hi = p[1];
                bf.u[0] = lo.x; bf.u[1] = lo.y; bf.u[2] = hi.x; bf.u[3] = hi.y;
                acc[ni] = __builtin_amdgcn_mfma_f32_16x16x32_bf16(af.v, bf.v, acc[ni], 0, 0, 0);
            }
        }
    }

    // C/D layout: col = lane&15, row = (lane>>4)*4 + reg  [guide m89]
    float* outp = pp + (size_t)blockIdx.z * PSTR;
    #pragma unroll
    for (int ni = 0; ni < 4; ++ni) {
        int col = e0 + ni * 16 + l15;
        #pragma unroll
        for (int r = 0; r < 4; ++r) {
            int row = row0 + wid * 16 + lk * 4 + r;
            outp[(size_t)row * DD + col] = acc[ni][r];
        }
    }
}

// ---------------------------------------------------------------------------
// Kernel 2: logits with FUSED split-K reduce + bias + scale during staging.
// [round-8 verified verbatim; launch_bounds 4 -> 6]
//   xs[d][a] = LOG2E2*(pp0 + pp1 + Wb)   (x-proj rows)
//   ms[d][b] = LOG2E2*(pp0 + pp1)        (m-proj rows)
//   wpart[dc][n][a][b] = sum_{d in chunk} V[d] * sig2(xs + ms)
// ---------------------------------------------------------------------------
__global__ __launch_bounds__(256, 6) void logits_kernel(
    const float* __restrict__ pp, const float* __restrict__ Wb,
    const float* __restrict__ Vw, float* __restrict__ wpart)
{
    __shared__ __attribute__((aligned(16))) float xs[64][34];  // [d][a: 32+2]
    __shared__ __attribute__((aligned(16))) float ms[64][68];  // [d][b: 64+4]
    __shared__ __attribute__((aligned(16))) float vsh[64];

    int n  = blockIdx.z;
    int bt = blockIdx.x;          // 0..3 : 64 b-cols
    int at = blockIdx.y & 3;      // 0..3 : 32 a-rows
    int dc = blockIdx.y >> 2;     // 0..7 : 64-d chunk
    int tid = threadIdx.x;
    int ty = tid >> 4, tx = tid & 15;

    // ---- stage x-part: 32 rows x 64 d, summing 2 planes, + bias, * scale
    {
        int r  = tid & 31;
        int c8 = (tid >> 5) * 8;
        size_t base = ((size_t)(n * LL0 + at * 32) + r) * DD + dc * 64 + c8;
        float4 p00 = *(const float4*)(pp + base);
        float4 p01 = *(const float4*)(pp + base + 4);
        float4 p10 = *(const float4*)(pp + PSTR + base);
        float4 p11 = *(const float4*)(pp + PSTR + base + 4);
        float4 w0  = *(const float4*)(Wb + dc * 64 + c8);
        float4 w1  = *(const float4*)(Wb + dc * 64 + c8 + 4);
        xs[c8 + 0][r] = LOG2E2 * (p00.x + p10.x + w0.x);
        xs[c8 + 1][r] = LOG2E2 * (p00.y + p10.y + w0.y);
        xs[c8 + 2][r] = LOG2E2 * (p00.z + p10.z + w0.z);
        xs[c8 + 3][r] = LOG2E2 * (p00.w + p10.w + w0.w);
        xs[c8 + 4][r] = LOG2E2 * (p01.x + p11.x + w1.x);
        xs[c8 + 5][r] = LOG2E2 * (p01.y + p11.y + w1.y);
        xs[c8 + 6][r] = LOG2E2 * (p01.z + p11.z + w1.z);
        xs[c8 + 7][r] = LOG2E2 * (p01.w + p11.w + w1.w);
    }
    // ---- stage m-part: 64 rows x 64 d (rows live at pp offset 1024 + n*256)
    {
        int r   = tid & 63;
        int c16 = (tid >> 6) * 16;
        size_t base = ((size_t)(NN * LL0 + n * LL1 + bt * 64) + r) * DD
                      + dc * 64 + c16;
        #pragma unroll
        for (int q = 0; q < 4; ++q) {
            float4 p0 = *(const float4*)(pp + base + q * 4);
            float4 p1 = *(const float4*)(pp + PSTR + base + q * 4);
            int c = c16 + q * 4;
            ms[c + 0][r] = LOG2E2 * (p0.x + p1.x);
            ms[c + 1][r] = LOG2E2 * (p0.y + p1.y);
            ms[c + 2][r] = LOG2E2 * (p0.z + p1.z);
            ms[c + 3][r] = LOG2E2 * (p0.w + p1.w);
        }
        if (tid < 16)
            *(float4*)&vsh[tid * 4] = *(const float4*)(Vw + dc * 64 + tid * 4);
    }
    __syncthreads();

    float acc[2][4] = {};

    #pragma unroll 8
    for (int kk = 0; kk < 64; ++kk) {
        float2 xa = *(const float2*)&xs[kk][ty * 2];
        float4 mb = *(const float4*)&ms[kk][tx * 4];
        float  vv = vsh[kk];
        float b_[4] = {mb.x, mb.y, mb.z, mb.w};
        #pragma unroll
        for (int j = 0; j < 4; ++j) {
            acc[0][j] = fmaf(vv, sig2(xa.x + b_[j]), acc[0][j]);
            acc[1][j] = fmaf(vv, sig2(xa.y + b_[j]), acc[1][j]);
        }
    }

    const size_t P = (size_t)NN * LL0 * LL1;
    float* wp = wpart + (size_t)dc * P
              + ((size_t)n * LL0 + at * 32 + ty * 2) * LL1 + bt * 64 + tx * 4;
    *(float4*)(wp)       = make_float4(acc[0][0], acc[0][1], acc[0][2], acc[0][3]);
    *(float4*)(wp + LL1) = make_float4(acc[1][0], acc[1][1], acc[1][2], acc[1][3]);
}

// ---------------------------------------------------------------------------
// Kernel 3: masked softmax over b (sums 8 d-chunk partials, -2 scale).
// ---------------------------------------------------------------------------
__global__ __launch_bounds__(256) void softmax_kernel(
    float* __restrict__ wpart, const int* __restrict__ mask)
{
    __shared__ float red[4];
    __shared__ float red2[4];
    const size_t P = (size_t)NN * LL0 * LL1;
    int row = blockIdx.x;          // n*L0 + a
    int n = row >> 7;
    int b = threadIdx.x;
    size_t idx = (size_t)row * LL1 + b;

    float s8 = 0.f;
    #pragma unroll
    for (int p = 0; p < 8; ++p) s8 += wpart[idx + (size_t)p * P];
    float w = -2.0f * s8;
    if (mask[n * LL1 + b] == 0) w = -1e30f;

    float mx = w;
    #pragma unroll
    for (int off = 32; off; off >>= 1) mx = fmaxf(mx, __shfl_xor(mx, off));
    int wv = threadIdx.x >> 6;
    if ((threadIdx.x & 63) == 0) red[wv] = mx;
    __syncthreads();
    mx = fmaxf(fmaxf(red[0], red[1]), fmaxf(red[2], red[3]));

    float e = (w > -1e29f) ? __expf(w - mx) : 0.f;
    float s = e;
    #pragma unroll
    for (int off = 32; off; off >>= 1) s += __shfl_xor(s, off);
    if ((threadIdx.x & 63) == 0) red2[wv] = s;
    __syncthreads();
    s = red2[0] + red2[1] + red2[2] + red2[3];

    wpart[idx] = e / s;            // dense write into plane 0 (reads done first)
}

// ---------------------------------------------------------------------------
// Kernel 4: v[n,a,d] = sum_b w[n,a,b] * m[n,b,d].  [verified]
// ---------------------------------------------------------------------------
__global__ __launch_bounds__(256, 4) void vgemm_kernel(
    const float* __restrict__ wbuf, const float* __restrict__ m,
    float* __restrict__ out)
{
    __shared__ float wt[32][36];   // [k][a: 32+4]
    __shared__ float mt[32][68];   // [k][d: 64+4]

    int n  = blockIdx.z;
    int a0 = blockIdx.y * 32;
    int d0 = blockIdx.x * 64;
    int tid = threadIdx.x;
    int ty = tid >> 4, tx = tid & 15;

    const float* wrow = wbuf + ((size_t)n * LL0 + a0) * LL1;
    const float* mrow = m + (size_t)n * LL1 * DD;

    float acc[2][4] = {};
    for (int k0 = 0; k0 < LL1; k0 += 32) {
        {
            int r  = tid >> 3;            // a-row 0..31
            int c4 = (tid & 7) * 4;       // k 0..28
            float4 wv = *(const float4*)(wrow + (size_t)r * LL1 + k0 + c4);
            wt[c4 + 0][r] = wv.x; wt[c4 + 1][r] = wv.y;
            wt[c4 + 2][r] = wv.z; wt[c4 + 3][r] = wv.w;
        }
        {
            int r  = tid >> 3;            // k-row 0..31
            int c8 = (tid & 7) * 8;       // d 0..56
            const float* src = mrow + (size_t)(k0 + r) * DD + d0 + c8;
            *(float4*)&mt[r][c8]     = *(const float4*)(src);
            *(float4*)&mt[r][c8 + 4] = *(const float4*)(src + 4);
        }
        __syncthreads();
        #pragma unroll 8
        for (int kk = 0; kk < 32; ++kk) {
            float2 av = *(const float2*)&wt[kk][ty * 2];
            float4 bv = *(const float4*)&mt[kk][tx * 4];
            acc[0][0] = fmaf(av.x, bv.x, acc[0][0]);
            acc[0][1] = fmaf(av.x, bv.y, acc[0][1]);
            acc[0][2] = fmaf(av.x, bv.z, acc[0][2]);
            acc[0][3] = fmaf(av.x, bv.w, acc[0][3]);
            acc[1][0] = fmaf(av.y, bv.x, acc[1][0]);
            acc[1][1] = fmaf(av.y, bv.y, acc[1][1]);
            acc[1][2] = fmaf(av.y, bv.z, acc[1][2]);
            acc[1][3] = fmaf(av.y, bv.w, acc[1][3]);
        }
        __syncthreads();
    }
    float* op = out + ((size_t)n * LL0 + a0 + ty * 2) * DD + d0 + tx * 4;
    *(float4*)(op)      = make_float4(acc[0][0], acc[0][1], acc[0][2], acc[0][3]);
    *(float4*)(op + DD) = make_float4(acc[1][0], acc[1][1], acc[1][2], acc[1][3]);
}

extern "C" void kernel_launch(void* const* d_in, const int* in_sizes, int n_in,
                              void* d_out, int out_size, void* d_ws, size_t ws_size,
                              hipStream_t stream) {
    const float* x    = (const float*)d_in[0];
    const float* m    = (const float*)d_in[1];
    const int*   mask = (const int*)d_in[2];
    const float* W_w  = (const float*)d_in[3];
    const float* W_b  = (const float*)d_in[4];
    const float* V_w  = (const float*)d_in[5];
    const float* V_b  = (const float*)d_in[6];
    (void)V_b; // additive constant — cancels under softmax shift-invariance
    float* out = (float*)d_out;

    // Workspace (floats):
    //   pp    : 2 * PSTR             = 3,145,728  (split-K projection partials)
    //   wpart : 8 * 8*128*256        = 2,097,152  (logit partials; plane 0 -> w)
    //   A16   : 3072*512 bf16        =   786,432  float-equiv
    //   W16   : 512*1024 bf16        =   262,144  float-equiv
    // Total: 6,291,456 floats = 25.2 MB
    float* pp    = (float*)d_ws;
    float* wpart = pp + 2 * PSTR;
    unsigned short* A16 = (unsigned short*)(wpart + (size_t)8 * NN * LL0 * LL1);
    unsigned short* W16 = A16 + (size_t)3072 * 512;

    cvt_kernel<<<dim3(2048), 256, 0, stream>>>(x, m, W_w, A16, W16);
    mfma_proj_kernel<<<dim3(8, 48, 2), 256, 0, stream>>>(A16, W16, pp);
    logits_kernel<<<dim3(4, 32, 8), 256, 0, stream>>>(pp, W_b, V_w, wpart);
    softmax_kernel<<<dim3(1024), 256, 0, stream>>>(wpart, mask);
    vgemm_kernel<<<dim3(8, 4, 8), 256, 0, stream>>>(wpart, m, out);
}

// Round 12
// 63.532 us; speedup vs baseline: 1.0382x; 1.0085x over previous
//
#include <hip/hip_runtime.h>
#include <hip/hip_bf16.h>

#define DD 512
#define NN 8
#define LL0 128
#define LL1 256

// 2 * log2(e): pre-scale so tanh(t) needs only v_exp_f32 (2^x).
#define LOG2E2 2.8853900817779268f

// split-K partial plane stride (floats): 3072 rows x 512 e
#define PSTR ((size_t)3072 * 512)

typedef float f32x4 __attribute__((ext_vector_type(4)));
typedef __bf16 bf16x8 __attribute__((ext_vector_type(8)));

__device__ __forceinline__ float fexp2(float x) {
#if __has_builtin(__builtin_amdgcn_exp2f)
    return __builtin_amdgcn_exp2f(x);
#else
    float r; asm("v_exp_f32 %0, %1" : "=v"(r) : "v"(x)); return r;
#endif
}
__device__ __forceinline__ float frcp(float x) {
#if __has_builtin(__builtin_amdgcn_rcpf)
    return __builtin_amdgcn_rcpf(x);
#else
    float r; asm("v_rcp_f32 %0, %1" : "=v"(r) : "v"(x)); return r;
#endif
}

// sigma2(t2) = 1/(2^t2 + 1); tanh(t) = 1 - 2*sigma2(2*log2e*t).
__device__ __forceinline__ float sig2(float t2) {
    return frcp(fexp2(t2) + 1.0f);
}

// fp32 -> bf16 round-to-nearest-even (normals; inputs are well-scaled).
__device__ __forceinline__ unsigned short f2bf(float f) {
    unsigned int u = __float_as_uint(f);
    u += 0x7fffu + ((u >> 16) & 1u);
    return (unsigned short)(u >> 16);
}

// ---------------------------------------------------------------------------
// Kernel 0: convert x|m -> A16[3072][512] bf16, W -> W16[512][1024] bf16.
// ---------------------------------------------------------------------------
__global__ __launch_bounds__(256) void cvt_kernel(
    const float* __restrict__ x, const float* __restrict__ m,
    const float* __restrict__ W,
    unsigned short* __restrict__ A16, unsigned short* __restrict__ W16)
{
    size_t i4 = ((size_t)blockIdx.x * 256 + threadIdx.x) * 4;
    const float* src;
    unsigned short* dst;
    if (i4 < (size_t)3072 * 512) {                 // A-part (x then m)
        src = (i4 < (size_t)1024 * 512) ? x + i4 : m + (i4 - (size_t)1024 * 512);
        dst = A16 + i4;
    } else {                                       // W-part
        size_t j = i4 - (size_t)3072 * 512;
        src = W + j; dst = W16 + j;
    }
    float4 v = *(const float4*)src;
    ushort4 o = make_ushort4(f2bf(v.x), f2bf(v.y), f2bf(v.z), f2bf(v.w));
    *(ushort4*)dst = o;
}

// ---------------------------------------------------------------------------
// Kernel 1: MFMA bf16 projection GEMM v3, split-K=2.  [r11 verbatim]
//   pp[kz][row][e] = sum_{k in half kz} A16[row][k] * W16[e][koff+k]
// 64x64 tile, K-step 64, 4 waves; 68-short row pad (136 B) -> b64 fragment
// reads are bank-optimal (per-quarter broadcast / even coverage).
// Grid (8, 48, 2) = 768 blocks = 3.0/CU exact.
// ---------------------------------------------------------------------------
__global__ __launch_bounds__(256, 3) void mfma_proj_kernel(
    const unsigned short* __restrict__ A16, const unsigned short* __restrict__ W16,
    float* __restrict__ pp)
{
    __shared__ unsigned short As[64][68];
    __shared__ unsigned short Bs[64][68];

    int e0   = blockIdx.x * 64;
    int row0 = blockIdx.y * 64;
    int kb0  = blockIdx.z * 256;       // K-half base
    bool isx = row0 < (NN * LL0);
    int koff = isx ? 0 : DD;

    int tid  = threadIdx.x;
    int wid  = tid >> 6;               // wave 0..3 -> rows wid*16..+15
    int lane = tid & 63;
    int l15  = lane & 15, lk = lane >> 4;   // lk 0..3

    int srow = tid >> 2;               // staging row 0..63
    int scol = (tid & 3) * 16;         // staging k-col (bf16 units)

    const unsigned short* Ap = A16 + (size_t)(row0 + srow) * DD + kb0 + scol;
    const unsigned short* Bp = W16 + (size_t)(e0 + srow) * (2 * DD) + koff + kb0 + scol;

    uint4 a0 = *(const uint4*)(Ap);
    uint4 a1 = *(const uint4*)(Ap + 8);
    uint4 b0 = *(const uint4*)(Bp);
    uint4 b1 = *(const uint4*)(Bp + 8);

    f32x4 acc[4] = {};

    for (int kt = 0; kt < 4; ++kt) {
        if (kt) __syncthreads();
        *(uint2*)&As[srow][scol + 0]  = make_uint2(a0.x, a0.y);
        *(uint2*)&As[srow][scol + 4]  = make_uint2(a0.z, a0.w);
        *(uint2*)&As[srow][scol + 8]  = make_uint2(a1.x, a1.y);
        *(uint2*)&As[srow][scol + 12] = make_uint2(a1.z, a1.w);
        *(uint2*)&Bs[srow][scol + 0]  = make_uint2(b0.x, b0.y);
        *(uint2*)&Bs[srow][scol + 4]  = make_uint2(b0.z, b0.w);
        *(uint2*)&Bs[srow][scol + 8]  = make_uint2(b1.x, b1.y);
        *(uint2*)&Bs[srow][scol + 12] = make_uint2(b1.z, b1.w);
        if (kt < 3) {
            int ko = (kt + 1) * 64;
            a0 = *(const uint4*)(Ap + ko);
            a1 = *(const uint4*)(Ap + ko + 8);
            b0 = *(const uint4*)(Bp + ko);
            b1 = *(const uint4*)(Bp + ko + 8);
        }
        __syncthreads();

        #pragma unroll
        for (int kb = 0; kb < 2; ++kb) {
            union { unsigned int u[4]; bf16x8 v; } af;
            {
                const uint2* p = (const uint2*)&As[wid * 16 + l15][kb * 32 + lk * 8];
                uint2 lo = p[0], hi = p[1];
                af.u[0] = lo.x; af.u[1] = lo.y; af.u[2] = hi.x; af.u[3] = hi.y;
            }
            #pragma unroll
            for (int ni = 0; ni < 4; ++ni) {
                union { unsigned int u[4]; bf16x8 v; } bf;
                const uint2* p = (const uint2*)&Bs[ni * 16 + l15][kb * 32 + lk * 8];
                uint2 lo = p[0], hi = p[1];
                bf.u[0] = lo.x; bf.u[1] = lo.y; bf.u[2] = hi.x; bf.u[3] = hi.y;
                acc[ni] = __builtin_amdgcn_mfma_f32_16x16x32_bf16(af.v, bf.v, acc[ni], 0, 0, 0);
            }
        }
    }

    // C/D layout: col = lane&15, row = (lane>>4)*4 + reg  [guide m89]
    float* outp = pp + (size_t)blockIdx.z * PSTR;
    #pragma unroll
    for (int ni = 0; ni < 4; ++ni) {
        int col = e0 + ni * 16 + l15;
        #pragma unroll
        for (int r = 0; r < 4; ++r) {
            int row = row0 + wid * 16 + lk * 4 + r;
            outp[(size_t)row * DD + col] = acc[ni][r];
        }
    }
}

// ---------------------------------------------------------------------------
// Kernel 2: logits, d-chunk 32, high occupancy (8 blocks/CU, 6 waves/SIMD).
// Fused split-K reduce + bias + scale during staging.
//   wpart[dc][n][a][b] = sum_{d in chunk dc} V[d] * sig2(xs + ms)
// LDS 13.2 KB. Grid (4, 64, 8) = 2048 blocks = 8.0/CU exact.
// ---------------------------------------------------------------------------
__global__ __launch_bounds__(256, 6) void logits_kernel(
    const float* __restrict__ pp, const float* __restrict__ Wb,
    const float* __restrict__ Vw, float* __restrict__ wpart)
{
    __shared__ __attribute__((aligned(16))) float xs[32][34];  // [d][a: 32+2]
    __shared__ __attribute__((aligned(16))) float ms[32][68];  // [d][b: 64+4]
    __shared__ __attribute__((aligned(16))) float vsh[32];

    int n  = blockIdx.z;
    int bt = blockIdx.x;          // 0..3  : 64 b-cols
    int at = blockIdx.y & 3;      // 0..3  : 32 a-rows
    int dc = blockIdx.y >> 2;     // 0..15 : 32-d chunk
    int tid = threadIdx.x;
    int ty = tid >> 4, tx = tid & 15;

    // ---- stage x-part: 32 rows x 32 d, sum 2 planes + bias, * scale
    {
        int r  = tid & 31;            // lane-major row -> conflict-free writes
        int c4 = (tid >> 5) * 4;      // 0..28
        size_t base = ((size_t)(n * LL0 + at * 32) + r) * DD + dc * 32 + c4;
        float4 p0 = *(const float4*)(pp + base);
        float4 p1 = *(const float4*)(pp + PSTR + base);
        float4 w0 = *(const float4*)(Wb + dc * 32 + c4);
        xs[c4 + 0][r] = LOG2E2 * (p0.x + p1.x + w0.x);
        xs[c4 + 1][r] = LOG2E2 * (p0.y + p1.y + w0.y);
        xs[c4 + 2][r] = LOG2E2 * (p0.z + p1.z + w0.z);
        xs[c4 + 3][r] = LOG2E2 * (p0.w + p1.w + w0.w);
    }
    // ---- stage m-part: 64 rows x 32 d (m-rows at pp offset 1024 + n*256)
    {
        int r  = tid & 63;            // lane-major row
        int c8 = (tid >> 6) * 8;      // 0,8,16,24
        size_t base = ((size_t)(NN * LL0 + n * LL1 + bt * 64) + r) * DD
                      + dc * 32 + c8;
        #pragma unroll
        for (int q = 0; q < 2; ++q) {
            float4 p0 = *(const float4*)(pp + base + q * 4);
            float4 p1 = *(const float4*)(pp + PSTR + base + q * 4);
            int c = c8 + q * 4;
            ms[c + 0][r] = LOG2E2 * (p0.x + p1.x);
            ms[c + 1][r] = LOG2E2 * (p0.y + p1.y);
            ms[c + 2][r] = LOG2E2 * (p0.z + p1.z);
            ms[c + 3][r] = LOG2E2 * (p0.w + p1.w);
        }
        if (tid < 8)
            *(float4*)&vsh[tid * 4] = *(const float4*)(Vw + dc * 32 + tid * 4);
    }
    __syncthreads();

    float acc[2][4] = {};

    #pragma unroll 8
    for (int kk = 0; kk < 32; ++kk) {
        float2 xa = *(const float2*)&xs[kk][ty * 2];   // 2 a-values (broadcast)
        float4 mb = *(const float4*)&ms[kk][tx * 4];   // 4 b-values (2-way free)
        float  vv = vsh[kk];
        float b_[4] = {mb.x, mb.y, mb.z, mb.w};
        #pragma unroll
        for (int j = 0; j < 4; ++j) {
            acc[0][j] = fmaf(vv, sig2(xa.x + b_[j]), acc[0][j]);
            acc[1][j] = fmaf(vv, sig2(xa.y + b_[j]), acc[1][j]);
        }
    }

    const size_t P = (size_t)NN * LL0 * LL1;
    float* wp = wpart + (size_t)dc * P
              + ((size_t)n * LL0 + at * 32 + ty * 2) * LL1 + bt * 64 + tx * 4;
    *(float4*)(wp)       = make_float4(acc[0][0], acc[0][1], acc[0][2], acc[0][3]);
    *(float4*)(wp + LL1) = make_float4(acc[1][0], acc[1][1], acc[1][2], acc[1][3]);
}

// ---------------------------------------------------------------------------
// Kernel 3: masked softmax over b, 16 partial planes, NO max pass
// (logit = -2*s16 is provably in [-23, 0]: exp cannot over/underflow).
// Masked -> exactly 0. Dense write into plane 0.
// ---------------------------------------------------------------------------
__global__ __launch_bounds__(256) void softmax_kernel(
    float* __restrict__ wpart, const int* __restrict__ mask)
{
    __shared__ float red2[4];
    const size_t P = (size_t)NN * LL0 * LL1;
    int row = blockIdx.x;          // n*L0 + a
    int n = row >> 7;
    int b = threadIdx.x;
    size_t idx = (size_t)row * LL1 + b;

    float s16 = 0.f;
    #pragma unroll
    for (int p = 0; p < 16; ++p) s16 += wpart[idx + (size_t)p * P];
    float w = -2.0f * s16;

    float e = (mask[n * LL1 + b] != 0) ? __expf(w) : 0.f;
    float s = e;
    #pragma unroll
    for (int off = 32; off; off >>= 1) s += __shfl_xor(s, off);
    int wv = threadIdx.x >> 6;
    if ((threadIdx.x & 63) == 0) red2[wv] = s;
    __syncthreads();
    s = red2[0] + red2[1] + red2[2] + red2[3];

    wpart[idx] = e / s;            // dense write into plane 0 (reads done first)
}

// ---------------------------------------------------------------------------
// Kernel 4: v[n,a,d] = sum_b w[n,a,b] * m[n,b,d].  [verified]
// ---------------------------------------------------------------------------
__global__ __launch_bounds__(256, 4) void vgemm_kernel(
    const float* __restrict__ wbuf, const float* __restrict__ m,
    float* __restrict__ out)
{
    __shared__ float wt[32][36];   // [k][a: 32+4]
    __shared__ float mt[32][68];   // [k][d: 64+4]

    int n  = blockIdx.z;
    int a0 = blockIdx.y * 32;
    int d0 = blockIdx.x * 64;
    int tid = threadIdx.x;
    int ty = tid >> 4, tx = tid & 15;

    const float* wrow = wbuf + ((size_t)n * LL0 + a0) * LL1;
    const float* mrow = m + (size_t)n * LL1 * DD;

    float acc[2][4] = {};
    for (int k0 = 0; k0 < LL1; k0 += 32) {
        {
            int r  = tid >> 3;            // a-row 0..31
            int c4 = (tid & 7) * 4;       // k 0..28
            float4 wv = *(const float4*)(wrow + (size_t)r * LL1 + k0 + c4);
            wt[c4 + 0][r] = wv.x; wt[c4 + 1][r] = wv.y;
            wt[c4 + 2][r] = wv.z; wt[c4 + 3][r] = wv.w;
        }
        {
            int r  = tid >> 3;            // k-row 0..31
            int c8 = (tid & 7) * 8;       // d 0..56
            const float* src = mrow + (size_t)(k0 + r) * DD + d0 + c8;
            *(float4*)&mt[r][c8]     = *(const float4*)(src);
            *(float4*)&mt[r][c8 + 4] = *(const float4*)(src + 4);
        }
        __syncthreads();
        #pragma unroll 8
        for (int kk = 0; kk < 32; ++kk) {
            float2 av = *(const float2*)&wt[kk][ty * 2];
            float4 bv = *(const float4*)&mt[kk][tx * 4];
            acc[0][0] = fmaf(av.x, bv.x, acc[0][0]);
            acc[0][1] = fmaf(av.x, bv.y, acc[0][1]);
            acc[0][2] = fmaf(av.x, bv.z, acc[0][2]);
            acc[0][3] = fmaf(av.x, bv.w, acc[0][3]);
            acc[1][0] = fmaf(av.y, bv.x, acc[1][0]);
            acc[1][1] = fmaf(av.y, bv.y, acc[1][1]);
            acc[1][2] = fmaf(av.y, bv.z, acc[1][2]);
            acc[1][3] = fmaf(av.y, bv.w, acc[1][3]);
        }
        __syncthreads();
    }
    float* op = out + ((size_t)n * LL0 + a0 + ty * 2) * DD + d0 + tx * 4;
    *(float4*)(op)      = make_float4(acc[0][0], acc[0][1], acc[0][2], acc[0][3]);
    *(float4*)(op + DD) = make_float4(acc[1][0], acc[1][1], acc[1][2], acc[1][3]);
}

extern "C" void kernel_launch(void* const* d_in, const int* in_sizes, int n_in,
                              void* d_out, int out_size, void* d_ws, size_t ws_size,
                              hipStream_t stream) {
    const float* x    = (const float*)d_in[0];
    const float* m    = (const float*)d_in[1];
    const int*   mask = (const int*)d_in[2];
    const float* W_w  = (const float*)d_in[3];
    const float* W_b  = (const float*)d_in[4];
    const float* V_w  = (const float*)d_in[5];
    const float* V_b  = (const float*)d_in[6];
    (void)V_b; // additive constant — cancels under softmax shift-invariance
    float* out = (float*)d_out;

    // Workspace (floats):
    //   pp    : 2 * PSTR             = 3,145,728
    //   wpart : 16 * 8*128*256       = 4,194,304  (plane 0 reused as w)
    //   A16   : 3072*512 bf16        =   786,432  float-equiv
    //   W16   : 512*1024 bf16        =   262,144  float-equiv
    // Total: 8,388,608 floats = 33.6 MB
    float* pp    = (float*)d_ws;
    float* wpart = pp + 2 * PSTR;
    unsigned short* A16 = (unsigned short*)(wpart + (size_t)16 * NN * LL0 * LL1);
    unsigned short* W16 = A16 + (size_t)3072 * 512;

    cvt_kernel<<<dim3(2048), 256, 0, stream>>>(x, m, W_w, A16, W16);
    mfma_proj_kernel<<<dim3(8, 48, 2), 256, 0, stream>>>(A16, W16, pp);
    logits_kernel<<<dim3(4, 64, 8), 256, 0, stream>>>(pp, W_b, V_w, wpart);
    softmax_kernel<<<dim3(1024), 256, 0, stream>>>(wpart, mask);
    vgemm_kernel<<<dim3(8, 4, 8), 256, 0, stream>>>(wpart, m, out);
}

// Round 13
// 50.067 us; speedup vs baseline: 1.3175x; 1.2689x over previous
//
#include <hip/hip_runtime.h>
#include <hip/hip_bf16.h>

#define DD 512
#define NN 8
#define LL0 128
#define LL1 256

// 2 * log2(e): pre-scale so tanh(t) needs only v_exp_f32 (2^x).
#define LOG2E2 2.8853900817779268f

// split-K partial plane stride (floats): 3072 rows x 512 e
#define PSTR ((size_t)3072 * 512)

typedef float f32x4 __attribute__((ext_vector_type(4)));
typedef __bf16 bf16x8 __attribute__((ext_vector_type(8)));

__device__ __forceinline__ float fexp2(float x) {
#if __has_builtin(__builtin_amdgcn_exp2f)
    return __builtin_amdgcn_exp2f(x);
#else
    float r; asm("v_exp_f32 %0, %1" : "=v"(r) : "v"(x)); return r;
#endif
}
__device__ __forceinline__ float frcp(float x) {
#if __has_builtin(__builtin_amdgcn_rcpf)
    return __builtin_amdgcn_rcpf(x);
#else
    float r; asm("v_rcp_f32 %0, %1" : "=v"(r) : "v"(x)); return r;
#endif
}

// fp32 -> bf16 round-to-nearest-even (normals; inputs are well-scaled).
__device__ __forceinline__ unsigned short f2bf(float f) {
    unsigned int u = __float_as_uint(f);
    u += 0x7fffu + ((u >> 16) & 1u);
    return (unsigned short)(u >> 16);
}

// ---------------------------------------------------------------------------
// Kernel 0: convert x|m -> A16[3072][512] bf16, W -> W16[512][1024] bf16.
// ---------------------------------------------------------------------------
__global__ __launch_bounds__(256) void cvt_kernel(
    const float* __restrict__ x, const float* __restrict__ m,
    const float* __restrict__ W,
    unsigned short* __restrict__ A16, unsigned short* __restrict__ W16)
{
    size_t i4 = ((size_t)blockIdx.x * 256 + threadIdx.x) * 4;
    const float* src;
    unsigned short* dst;
    if (i4 < (size_t)3072 * 512) {                 // A-part (x then m)
        src = (i4 < (size_t)1024 * 512) ? x + i4 : m + (i4 - (size_t)1024 * 512);
        dst = A16 + i4;
    } else {                                       // W-part
        size_t j = i4 - (size_t)3072 * 512;
        src = W + j; dst = W16 + j;
    }
    float4 v = *(const float4*)src;
    ushort4 o = make_ushort4(f2bf(v.x), f2bf(v.y), f2bf(v.z), f2bf(v.w));
    *(ushort4*)dst = o;
}

// ---------------------------------------------------------------------------
// Kernel 1: MFMA bf16 projection GEMM v3, split-K=2.  [r11/r12 verbatim]
//   pp[kz][row][e] = sum_{k in half kz} A16[row][k] * W16[e][koff+k]
// 64x64 tile, K-step 64, 4 waves; 68-short row pad (136 B) -> b64 fragment
// reads bank-optimal. Grid (8, 48, 2) = 768 blocks = 3.0/CU exact.
// ---------------------------------------------------------------------------
__global__ __launch_bounds__(256, 3) void mfma_proj_kernel(
    const unsigned short* __restrict__ A16, const unsigned short* __restrict__ W16,
    float* __restrict__ pp)
{
    __shared__ unsigned short As[64][68];
    __shared__ unsigned short Bs[64][68];

    int e0   = blockIdx.x * 64;
    int row0 = blockIdx.y * 64;
    int kb0  = blockIdx.z * 256;       // K-half base
    bool isx = row0 < (NN * LL0);
    int koff = isx ? 0 : DD;

    int tid  = threadIdx.x;
    int wid  = tid >> 6;               // wave 0..3 -> rows wid*16..+15
    int lane = tid & 63;
    int l15  = lane & 15, lk = lane >> 4;   // lk 0..3

    int srow = tid >> 2;               // staging row 0..63
    int scol = (tid & 3) * 16;         // staging k-col (bf16 units)

    const unsigned short* Ap = A16 + (size_t)(row0 + srow) * DD + kb0 + scol;
    const unsigned short* Bp = W16 + (size_t)(e0 + srow) * (2 * DD) + koff + kb0 + scol;

    uint4 a0 = *(const uint4*)(Ap);
    uint4 a1 = *(const uint4*)(Ap + 8);
    uint4 b0 = *(const uint4*)(Bp);
    uint4 b1 = *(const uint4*)(Bp + 8);

    f32x4 acc[4] = {};

    for (int kt = 0; kt < 4; ++kt) {
        if (kt) __syncthreads();
        *(uint2*)&As[srow][scol + 0]  = make_uint2(a0.x, a0.y);
        *(uint2*)&As[srow][scol + 4]  = make_uint2(a0.z, a0.w);
        *(uint2*)&As[srow][scol + 8]  = make_uint2(a1.x, a1.y);
        *(uint2*)&As[srow][scol + 12] = make_uint2(a1.z, a1.w);
        *(uint2*)&Bs[srow][scol + 0]  = make_uint2(b0.x, b0.y);
        *(uint2*)&Bs[srow][scol + 4]  = make_uint2(b0.z, b0.w);
        *(uint2*)&Bs[srow][scol + 8]  = make_uint2(b1.x, b1.y);
        *(uint2*)&Bs[srow][scol + 12] = make_uint2(b1.z, b1.w);
        if (kt < 3) {
            int ko = (kt + 1) * 64;
            a0 = *(const uint4*)(Ap + ko);
            a1 = *(const uint4*)(Ap + ko + 8);
            b0 = *(const uint4*)(Bp + ko);
            b1 = *(const uint4*)(Bp + ko + 8);
        }
        __syncthreads();

        #pragma unroll
        for (int kb = 0; kb < 2; ++kb) {
            union { unsigned int u[4]; bf16x8 v; } af;
            {
                const uint2* p = (const uint2*)&As[wid * 16 + l15][kb * 32 + lk * 8];
                uint2 lo = p[0], hi = p[1];
                af.u[0] = lo.x; af.u[1] = lo.y; af.u[2] = hi.x; af.u[3] = hi.y;
            }
            #pragma unroll
            for (int ni = 0; ni < 4; ++ni) {
                union { unsigned int u[4]; bf16x8 v; } bf;
                const uint2* p = (const uint2*)&Bs[ni * 16 + l15][kb * 32 + lk * 8];
                uint2 lo = p[0], hi = p[1];
                bf.u[0] = lo.x; bf.u[1] = lo.y; bf.u[2] = hi.x; bf.u[3] = hi.y;
                acc[ni] = __builtin_amdgcn_mfma_f32_16x16x32_bf16(af.v, bf.v, acc[ni], 0, 0, 0);
            }
        }
    }

    // C/D layout: col = lane&15, row = (lane>>4)*4 + reg  [guide m89]
    float* outp = pp + (size_t)blockIdx.z * PSTR;
    #pragma unroll
    for (int ni = 0; ni < 4; ++ni) {
        int col = e0 + ni * 16 + l15;
        #pragma unroll
        for (int r = 0; r < 4; ++r) {
            int row = row0 + wid * 16 + lk * 4 + r;
            outp[(size_t)row * DD + col] = acc[ni][r];
        }
    }
}

// ---------------------------------------------------------------------------
// Kernel 2: logits with EXP-PRECOMPUTED staging + paired rcp.
// Staging computes EX = 2^(LOG2E2*(pp0+pp1+Wb)) (x-rows) and
// EM = 2^(LOG2E2*(pp0+pp1)) (m-rows): 3072 exps/block vs 65536 elements.
// Inner: sig2 = 1/fma(EX,EM,1); pairs over d share one v_rcp:
//   V0/D0 + V1/D1 = (V0*D1 + V1*D0) / (D0*D1)
// Trans/elem: 2.0 -> ~0.55. Tile 32a x 64b x 64d, 2a x 4b micro-tile.
// Grid (4, 32, 8) = 1024 = 4/CU; LDS 26.4 KB.
// ---------------------------------------------------------------------------
__global__ __launch_bounds__(256, 4) void logits_kernel(
    const float* __restrict__ pp, const float* __restrict__ Wb,
    const float* __restrict__ Vw, float* __restrict__ wpart)
{
    __shared__ __attribute__((aligned(16))) float xs[64][34];  // [d][a] = EX
    __shared__ __attribute__((aligned(16))) float ms[64][68];  // [d][b] = EM
    __shared__ __attribute__((aligned(16))) float vsh[64];

    int n  = blockIdx.z;
    int bt = blockIdx.x;          // 0..3 : 64 b-cols
    int at = blockIdx.y & 3;      // 0..3 : 32 a-rows
    int dc = blockIdx.y >> 2;     // 0..7 : 64-d chunk
    int tid = threadIdx.x;
    int ty = tid >> 4, tx = tid & 15;

    // ---- stage x-part: 32 rows x 64 d -> EX (sum 2 planes + bias, scale, exp2)
    {
        int r  = tid & 31;
        int c8 = (tid >> 5) * 8;
        size_t base = ((size_t)(n * LL0 + at * 32) + r) * DD + dc * 64 + c8;
        float4 p00 = *(const float4*)(pp + base);
        float4 p01 = *(const float4*)(pp + base + 4);
        float4 p10 = *(const float4*)(pp + PSTR + base);
        float4 p11 = *(const float4*)(pp + PSTR + base + 4);
        float4 w0  = *(const float4*)(Wb + dc * 64 + c8);
        float4 w1  = *(const float4*)(Wb + dc * 64 + c8 + 4);
        xs[c8 + 0][r] = fexp2(LOG2E2 * (p00.x + p10.x + w0.x));
        xs[c8 + 1][r] = fexp2(LOG2E2 * (p00.y + p10.y + w0.y));
        xs[c8 + 2][r] = fexp2(LOG2E2 * (p00.z + p10.z + w0.z));
        xs[c8 + 3][r] = fexp2(LOG2E2 * (p00.w + p10.w + w0.w));
        xs[c8 + 4][r] = fexp2(LOG2E2 * (p01.x + p11.x + w1.x));
        xs[c8 + 5][r] = fexp2(LOG2E2 * (p01.y + p11.y + w1.y));
        xs[c8 + 6][r] = fexp2(LOG2E2 * (p01.z + p11.z + w1.z));
        xs[c8 + 7][r] = fexp2(LOG2E2 * (p01.w + p11.w + w1.w));
    }
    // ---- stage m-part: 64 rows x 64 d -> EM
    {
        int r   = tid & 63;
        int c16 = (tid >> 6) * 16;
        size_t base = ((size_t)(NN * LL0 + n * LL1 + bt * 64) + r) * DD
                      + dc * 64 + c16;
        #pragma unroll
        for (int q = 0; q < 4; ++q) {
            float4 p0 = *(const float4*)(pp + base + q * 4);
            float4 p1 = *(const float4*)(pp + PSTR + base + q * 4);
            int c = c16 + q * 4;
            ms[c + 0][r] = fexp2(LOG2E2 * (p0.x + p1.x));
            ms[c + 1][r] = fexp2(LOG2E2 * (p0.y + p1.y));
            ms[c + 2][r] = fexp2(LOG2E2 * (p0.z + p1.z));
            ms[c + 3][r] = fexp2(LOG2E2 * (p0.w + p1.w));
        }
        if (tid < 16)
            *(float4*)&vsh[tid * 4] = *(const float4*)(Vw + dc * 64 + tid * 4);
    }
    __syncthreads();

    float acc[2][4] = {};

    #pragma unroll 4
    for (int kk = 0; kk < 64; kk += 2) {
        float2 xa0 = *(const float2*)&xs[kk][ty * 2];      // EX, d = kk
        float2 xa1 = *(const float2*)&xs[kk + 1][ty * 2];  // EX, d = kk+1
        float4 mb0 = *(const float4*)&ms[kk][tx * 4];      // EM, d = kk
        float4 mb1 = *(const float4*)&ms[kk + 1][tx * 4];  // EM, d = kk+1
        float2 vv  = *(const float2*)&vsh[kk];
        float e0_[2] = {xa0.x, xa0.y};
        float e1_[2] = {xa1.x, xa1.y};
        float f0_[4] = {mb0.x, mb0.y, mb0.z, mb0.w};
        float f1_[4] = {mb1.x, mb1.y, mb1.z, mb1.w};
        #pragma unroll
        for (int i = 0; i < 2; ++i) {
            #pragma unroll
            for (int j = 0; j < 4; ++j) {
                float D0 = fmaf(e0_[i], f0_[j], 1.0f);
                float D1 = fmaf(e1_[i], f1_[j], 1.0f);
                float N  = fmaf(vv.x, D1, vv.y * D0);
                acc[i][j] = fmaf(N, frcp(D0 * D1), acc[i][j]);
            }
        }
    }

    const size_t P = (size_t)NN * LL0 * LL1;
    float* wp = wpart + (size_t)dc * P
              + ((size_t)n * LL0 + at * 32 + ty * 2) * LL1 + bt * 64 + tx * 4;
    *(float4*)(wp)       = make_float4(acc[0][0], acc[0][1], acc[0][2], acc[0][3]);
    *(float4*)(wp + LL1) = make_float4(acc[1][0], acc[1][1], acc[1][2], acc[1][3]);
}

// ---------------------------------------------------------------------------
// Kernel 3: masked softmax over b, 8 partial planes, no max pass
// (logit = -2*s8 bounded by +-2*sum|V| ~ 45: exp cannot over/underflow fp32).
// Masked -> exactly 0. Dense write into plane 0.
// ---------------------------------------------------------------------------
__global__ __launch_bounds__(256) void softmax_kernel(
    float* __restrict__ wpart, const int* __restrict__ mask)
{
    __shared__ float red2[4];
    const size_t P = (size_t)NN * LL0 * LL1;
    int row = blockIdx.x;          // n*L0 + a
    int n = row >> 7;
    int b = threadIdx.x;
    size_t idx = (size_t)row * LL1 + b;

    float s8 = 0.f;
    #pragma unroll
    for (int p = 0; p < 8; ++p) s8 += wpart[idx + (size_t)p * P];
    float w = -2.0f * s8;

    float e = (mask[n * LL1 + b] != 0) ? __expf(w) : 0.f;
    float s = e;
    #pragma unroll
    for (int off = 32; off; off >>= 1) s += __shfl_xor(s, off);
    int wv = threadIdx.x >> 6;
    if ((threadIdx.x & 63) == 0) red2[wv] = s;
    __syncthreads();
    s = red2[0] + red2[1] + red2[2] + red2[3];

    wpart[idx] = e / s;            // dense write into plane 0 (reads done first)
}

// ---------------------------------------------------------------------------
// Kernel 4: v[n,a,d] = sum_b w[n,a,b] * m[n,b,d].  [verified]
// ---------------------------------------------------------------------------
__global__ __launch_bounds__(256, 4) void vgemm_kernel(
    const float* __restrict__ wbuf, const float* __restrict__ m,
    float* __restrict__ out)
{
    __shared__ float wt[32][36];   // [k][a: 32+4]
    __shared__ float mt[32][68];   // [k][d: 64+4]

    int n  = blockIdx.z;
    int a0 = blockIdx.y * 32;
    int d0 = blockIdx.x * 64;
    int tid = threadIdx.x;
    int ty = tid >> 4, tx = tid & 15;

    const float* wrow = wbuf + ((size_t)n * LL0 + a0) * LL1;
    const float* mrow = m + (size_t)n * LL1 * DD;

    float acc[2][4] = {};
    for (int k0 = 0; k0 < LL1; k0 += 32) {
        {
            int r  = tid >> 3;            // a-row 0..31
            int c4 = (tid & 7) * 4;       // k 0..28
            float4 wv = *(const float4*)(wrow + (size_t)r * LL1 + k0 + c4);
            wt[c4 + 0][r] = wv.x; wt[c4 + 1][r] = wv.y;
            wt[c4 + 2][r] = wv.z; wt[c4 + 3][r] = wv.w;
        }
        {
            int r  = tid >> 3;            // k-row 0..31
            int c8 = (tid & 7) * 8;       // d 0..56
            const float* src = mrow + (size_t)(k0 + r) * DD + d0 + c8;
            *(float4*)&mt[r][c8]     = *(const float4*)(src);
            *(float4*)&mt[r][c8 + 4] = *(const float4*)(src + 4);
        }
        __syncthreads();
        #pragma unroll 8
        for (int kk = 0; kk < 32; ++kk) {
            float2 av = *(const float2*)&wt[kk][ty * 2];
            float4 bv = *(const float4*)&mt[kk][tx * 4];
            acc[0][0] = fmaf(av.x, bv.x, acc[0][0]);
            acc[0][1] = fmaf(av.x, bv.y, acc[0][1]);
            acc[0][2] = fmaf(av.x, bv.z, acc[0][2]);
            acc[0][3] = fmaf(av.x, bv.w, acc[0][3]);
            acc[1][0] = fmaf(av.y, bv.x, acc[1][0]);
            acc[1][1] = fmaf(av.y, bv.y, acc[1][1]);
            acc[1][2] = fmaf(av.y, bv.z, acc[1][2]);
            acc[1][3] = fmaf(av.y, bv.w, acc[1][3]);
        }
        __syncthreads();
    }
    float* op = out + ((size_t)n * LL0 + a0 + ty * 2) * DD + d0 + tx * 4;
    *(float4*)(op)      = make_float4(acc[0][0], acc[0][1], acc[0][2], acc[0][3]);
    *(float4*)(op + DD) = make_float4(acc[1][0], acc[1][1], acc[1][2], acc[1][3]);
}

extern "C" void kernel_launch(void* const* d_in, const int* in_sizes, int n_in,
                              void* d_out, int out_size, void* d_ws, size_t ws_size,
                              hipStream_t stream) {
    const float* x    = (const float*)d_in[0];
    const float* m    = (const float*)d_in[1];
    const int*   mask = (const int*)d_in[2];
    const float* W_w  = (const float*)d_in[3];
    const float* W_b  = (const float*)d_in[4];
    const float* V_w  = (const float*)d_in[5];
    const float* V_b  = (const float*)d_in[6];
    (void)V_b; // additive constant — cancels under softmax shift-invariance
    float* out = (float*)d_out;

    // Workspace (floats):
    //   pp    : 2 * PSTR             = 3,145,728
    //   wpart : 8 * 8*128*256        = 2,097,152  (plane 0 reused as w)
    //   A16   : 3072*512 bf16        =   786,432  float-equiv
    //   W16   : 512*1024 bf16        =   262,144  float-equiv
    // Total: 6,291,456 floats = 25.2 MB
    float* pp    = (float*)d_ws;
    float* wpart = pp + 2 * PSTR;
    unsigned short* A16 = (unsigned short*)(wpart + (size_t)8 * NN * LL0 * LL1);
    unsigned short* W16 = A16 + (size_t)3072 * 512;

    cvt_kernel<<<dim3(2048), 256, 0, stream>>>(x, m, W_w, A16, W16);
    mfma_proj_kernel<<<dim3(8, 48, 2), 256, 0, stream>>>(A16, W16, pp);
    logits_kernel<<<dim3(4, 32, 8), 256, 0, stream>>>(pp, W_b, V_w, wpart);
    softmax_kernel<<<dim3(1024), 256, 0, stream>>>(wpart, mask);
    vgemm_kernel<<<dim3(8, 4, 8), 256, 0, stream>>>(wpart, m, out);
}